// Round 1
// baseline (2304.066 us; speedup 1.0000x reference)
//
#include <hip/hip_runtime.h>
#include <hip/hip_bf16.h>
#include <cstdint>
#include <cstddef>

#define M_DIM 8192
#define K_DIM 4096
#define N_DIM 16384

typedef __attribute__((ext_vector_type(8))) short short8;
typedef __attribute__((ext_vector_type(4))) float floatx4;

// async global->LDS, 16B per lane. LDS dest must be wave-uniform base (+lane*16 by HW).
__device__ inline void gl2lds16(const void* g, void* l) {
  __builtin_amdgcn_global_load_lds(
      (const __attribute__((address_space(1))) void*)g,
      (__attribute__((address_space(3))) void*)l, 16, 0, 0);
}

// ---------------- Kernel 1: sum(|W|) in double ----------------
__global__ void abssum_kernel(const float* __restrict__ w, double* __restrict__ out) {
  size_t tid = (size_t)blockIdx.x * blockDim.x + threadIdx.x;
  size_t stride = (size_t)gridDim.x * blockDim.x;
  const float4* w4 = (const float4*)w;
  const size_t n4 = (size_t)N_DIM * K_DIM / 4;
  double s = 0.0;
  for (size_t i = tid; i < n4; i += stride) {
    float4 v = w4[i];
    s += (double)fabsf(v.x) + (double)fabsf(v.y) + (double)fabsf(v.z) + (double)fabsf(v.w);
  }
  // wave reduce (64 lanes)
  #pragma unroll
  for (int off = 32; off > 0; off >>= 1) s += __shfl_down(s, off, 64);
  if ((threadIdx.x & 63) == 0) atomicAdd(out, s);
}

// ---------------- Kernel 2: ternarize W -> bf16 (as ushort bits) ----------------
__global__ void ternarize_kernel(const float* __restrict__ w, ushort* __restrict__ tw,
                                 const double* __restrict__ sum) {
  const float thr = (float)(0.5 * (*sum) / (double)((size_t)N_DIM * K_DIM));
  size_t i = ((size_t)blockIdx.x * blockDim.x + threadIdx.x) * 8;
  float4 a = *(const float4*)(w + i);
  float4 b = *(const float4*)(w + i + 4);
  float v[8] = {a.x, a.y, a.z, a.w, b.x, b.y, b.z, b.w};
  union { ushort u[8]; uint4 q; } o;
  #pragma unroll
  for (int j = 0; j < 8; j++) {
    float av = fabsf(v[j]);
    o.u[j] = (av >= thr) ? ((v[j] > 0.0f) ? (ushort)0x3F80 : (ushort)0xBF80) : (ushort)0;
  }
  *(uint4*)(tw + i) = o.q;
}

// ---------------- Kernel 3: cast x -> bf16 (RNE) ----------------
__device__ inline ushort f2bf(float f) {
  uint32_t u = __float_as_uint(f);
  return (ushort)((u + 0x7FFFu + ((u >> 16) & 1u)) >> 16);
}
__global__ void bf16cast_kernel(const float* __restrict__ x, ushort* __restrict__ xb) {
  size_t i = ((size_t)blockIdx.x * blockDim.x + threadIdx.x) * 8;
  float4 a = *(const float4*)(x + i);
  float4 b = *(const float4*)(x + i + 4);
  float v[8] = {a.x, a.y, a.z, a.w, b.x, b.y, b.z, b.w};
  union { ushort u[8]; uint4 q; } o;
  #pragma unroll
  for (int j = 0; j < 8; j++) o.u[j] = f2bf(v[j]);
  *(uint4*)(xb + i) = o.q;
}

// ---------------- Kernel 4: C[m,n] = sum_k A[m,k]*B[n,k] + bias[n] ----------------
// A: [M,K] bf16 row-major, B: [N,K] bf16 row-major (B^T GEMM), C: [M,N] fp32.
// 128x128 tile, BK=32, 256 threads (4 waves), each wave a 64x64 quadrant (4x4 MFMA 16x16x32).
__global__ void gemm_bt_kernel(const ushort* __restrict__ A, const ushort* __restrict__ B,
                               const float* __restrict__ bias, float* __restrict__ C) {
  __shared__ __align__(16) ushort As[128 * 32];
  __shared__ __align__(16) ushort Bs[128 * 32];

  const int tid  = threadIdx.x;
  const int wave = tid >> 6;
  const int lane = tid & 63;
  const int bm = blockIdx.y, bn = blockIdx.x;
  const int wm = (wave >> 1) * 64;   // wave's m-quadrant
  const int wn = (wave & 1) * 64;    // wave's n-quadrant

  // staging geometry: per pass, each wave stages 16 rows x 32 cols (1 KiB).
  // lane i -> row (lane>>2), k-col (lane&3)*8 within the chunk (HW: base + lane*16B).
  const int srow = wave * 16 + (lane >> 2);
  const int scol = (lane & 3) * 8;
  const ushort* gA0 = A + (size_t)(bm * 128 + srow) * K_DIM + scol;
  const ushort* gA1 = gA0 + (size_t)64 * K_DIM;
  const ushort* gB0 = B + (size_t)(bn * 128 + srow) * K_DIM + scol;
  const ushort* gB1 = gB0 + (size_t)64 * K_DIM;
  ushort* lA0 = As + (wave * 16) * 32;          // wave-uniform LDS bases
  ushort* lA1 = As + (64 + wave * 16) * 32;
  ushort* lB0 = Bs + (wave * 16) * 32;
  ushort* lB1 = Bs + (64 + wave * 16) * 32;

  floatx4 acc[4][4];
  #pragma unroll
  for (int i = 0; i < 4; i++)
    #pragma unroll
    for (int j = 0; j < 4; j++)
      acc[i][j] = (floatx4){0.f, 0.f, 0.f, 0.f};

  const int r16 = lane & 15;
  const int quad = lane >> 4;

  for (int k0 = 0; k0 < K_DIM; k0 += 32) {
    __syncthreads();   // protect LDS from overwrite while prior iter still reading
    gl2lds16(gA0, lA0); gl2lds16(gA1, lA1);
    gl2lds16(gB0, lB0); gl2lds16(gB1, lB1);
    gA0 += 32; gA1 += 32; gB0 += 32; gB1 += 32;
    __syncthreads();   // staging complete (compiler drains vmcnt before barrier)

    short8 af[4], bf[4];
    #pragma unroll
    for (int i = 0; i < 4; i++)
      af[i] = *(const short8*)(As + (wm + i * 16 + r16) * 32 + quad * 8);
    #pragma unroll
    for (int j = 0; j < 4; j++)
      bf[j] = *(const short8*)(Bs + (wn + j * 16 + r16) * 32 + quad * 8);

    #pragma unroll
    for (int i = 0; i < 4; i++)
      #pragma unroll
      for (int j = 0; j < 4; j++)
        acc[i][j] = __builtin_amdgcn_mfma_f32_16x16x32_bf16(af[i], bf[j], acc[i][j], 0, 0, 0);
  }

  // epilogue: C/D layout col=lane&15, row=quad*4+reg  (m89/m91-verified)
  #pragma unroll
  for (int j = 0; j < 4; j++) {
    const int col = bn * 128 + wn + j * 16 + r16;
    const float bv = bias[col];
    #pragma unroll
    for (int i = 0; i < 4; i++) {
      const int row0 = bm * 128 + wm + i * 16 + quad * 4;
      #pragma unroll
      for (int r = 0; r < 4; r++)
        C[(size_t)(row0 + r) * N_DIM + col] = acc[i][j][r] + bv;
    }
  }
}

extern "C" void kernel_launch(void* const* d_in, const int* in_sizes, int n_in,
                              void* d_out, int out_size, void* d_ws, size_t ws_size,
                              hipStream_t stream) {
  const float* x    = (const float*)d_in[0];   // [8192, 4096]
  const float* w    = (const float*)d_in[1];   // [16384, 4096]
  const float* bias = (const float*)d_in[2];   // [16384]
  float* out = (float*)d_out;                  // [8192, 16384]

  char* ws = (char*)d_ws;
  double* sum = (double*)ws;                                        // 8 B
  ushort* xb  = (ushort*)(ws + 256);                                // 64 MiB
  ushort* tw  = (ushort*)(ws + 256 + (size_t)M_DIM * K_DIM * 2);    // 128 MiB

  hipMemsetAsync(sum, 0, sizeof(double), stream);
  abssum_kernel<<<2048, 256, 0, stream>>>(w, sum);
  ternarize_kernel<<<(size_t)N_DIM * K_DIM / 8 / 256, 256, 0, stream>>>(w, tw, sum);
  bf16cast_kernel<<<(size_t)M_DIM * K_DIM / 8 / 256, 256, 0, stream>>>(x, xb);

  dim3 grid(N_DIM / 128, M_DIM / 128);
  gemm_bt_kernel<<<grid, 256, 0, stream>>>(xb, tw, bias, out);
}